// Round 3
// baseline (1667.865 us; speedup 1.0000x reference)
//
#include <hip/hip_runtime.h>
#include <hip/hip_bf16.h>

// bf16 carried as short bit-patterns; MFMA frags as __bf16 vectors (gfx950 builtin sig V8y).
typedef __bf16 bf16x8 __attribute__((ext_vector_type(8)));
typedef short  s16x8  __attribute__((ext_vector_type(8)));
typedef float  f32x4  __attribute__((ext_vector_type(4)));

__device__ __forceinline__ float bf2f(short u) {
    unsigned x = ((unsigned)(unsigned short)u) << 16;
    float f; __builtin_memcpy(&f, &x, 4); return f;
}
__device__ __forceinline__ short f2bf(float f) {
    unsigned u; __builtin_memcpy(&u, &f, 4);
    unsigned r = (u + 0x7fff + ((u >> 16) & 1)) >> 16;   // RNE
    return (short)r;
}
// norm1_w/norm2_w == ones(E). fp32 1.0f low short = 0x0000; bf16 1.0 = 0x3F80.
__device__ __forceinline__ bool src_is_f32(const void* ones_w) {
    return ((const unsigned short*)ones_w)[0] == 0;
}

// ---------------- RoPE: qf = rope(x); xbf = bf16 copy of x ----------------
__global__ __launch_bounds__(256) void rope_kernel(const void* __restrict__ xv, short* __restrict__ qf,
                                                   short* __restrict__ xbf, const void* __restrict__ n1w) {
    bool f32 = src_is_f32(n1w);
    int idx = blockIdx.x * 256 + threadIdx.x;      // 4096 tokens * 16 heads * 64 pairs
    int i    = idx & 63;
    int head = (idx >> 6) & 15;
    int t    = idx >> 10;                          // 0..4095
    int pos  = t & 2047;
    float inv = __expf(-9.210340371976184f * (float)i * (1.0f / 64.0f)); // 10000^(-i/64)
    float fr = (float)pos * inv;
    float s, c; sincosf(fr, &s, &c);
    long base = (long)t * 2048 + head * 128 + i;
    float v1, v2;
    if (f32) { v1 = ((const float*)xv)[base]; v2 = ((const float*)xv)[base + 64]; }
    else     { v1 = bf2f(((const short*)xv)[base]); v2 = bf2f(((const short*)xv)[base + 64]); }
    qf[base]      = f2bf(v1 * c - v2 * s);
    qf[base + 64] = f2bf(v2 * c + v1 * s);
    xbf[base]      = f2bf(v1);
    xbf[base + 64] = f2bf(v2);
}

// ---------------- transpose: src[R][C] (elem offset soff, lead dim ld, fp32-or-bf16) -> dst[C][R] bf16 ----------------
__global__ __launch_bounds__(256) void transpose_any(const void* __restrict__ src, long soff, short* __restrict__ dst,
                                                     int R, int C, int ld, const void* __restrict__ n1w, int force_bf16) {
    bool f32 = force_bf16 ? false : src_is_f32(n1w);
    __shared__ short tile[32][33];
    int tx = threadIdx.x & 31, ty = threadIdx.x >> 5;   // 32 x 8
    int c0 = blockIdx.x * 32, r0 = blockIdx.y * 32;
    #pragma unroll
    for (int i = 0; i < 32; i += 8) {
        long p = soff + (long)(r0 + ty + i) * ld + c0 + tx;
        tile[ty + i][tx] = f32 ? f2bf(((const float*)src)[p]) : ((const short*)src)[p];
    }
    __syncthreads();
    #pragma unroll
    for (int i = 0; i < 32; i += 8) dst[(long)(c0 + ty + i) * R + r0 + tx] = tile[tx][ty + i];
}

// ---------------- NT GEMM: C[M,N] = A[M,K] @ Bt[N,K]^T, bf16 in/out, fp32 acc ----------------
// A lead dim lda, C lead dim ldc, Bt lead dim = K (dense).
// GEGLU=1: C already holds 'a'; write gelu_exact(a) * acc. ACCUM=1: C += acc.
template<int GEGLU, int ACCUM>
__global__ __launch_bounds__(256) void gemm_nt(const short* __restrict__ A, int lda, const short* __restrict__ Bt,
                                               short* __restrict__ C, int ldc, int M, int N, int K) {
    __shared__ short As[128 * 72];
    __shared__ short Bs[128 * 72];
    int tid = threadIdx.x;
    int w = tid >> 6, lane = tid & 63, quad = lane >> 4, l15 = lane & 15;
    int m0 = blockIdx.y * 128, n0 = blockIdx.x * 128;
    int wr = (w >> 1) * 64, wc = (w & 1) * 64;
    f32x4 acc[4][4] = {};
    for (int k0 = 0; k0 < K; k0 += 64) {
        __syncthreads();
        #pragma unroll
        for (int i = 0; i < 4; ++i) {
            int chunk = i * 256 + tid;
            int row = chunk >> 3, col = (chunk & 7) * 8;
            *(s16x8*)&As[row * 72 + col] = *(const s16x8*)&A [(long)(m0 + row) * lda + k0 + col];
            *(s16x8*)&Bs[row * 72 + col] = *(const s16x8*)&Bt[(long)(n0 + row) * K   + k0 + col];
        }
        __syncthreads();
        #pragma unroll
        for (int kk = 0; kk < 64; kk += 32) {
            bf16x8 a[4], b[4];
            #pragma unroll
            for (int i = 0; i < 4; ++i) a[i] = *(const bf16x8*)&As[(wr + 16 * i + l15) * 72 + kk + quad * 8];
            #pragma unroll
            for (int j = 0; j < 4; ++j) b[j] = *(const bf16x8*)&Bs[(wc + 16 * j + l15) * 72 + kk + quad * 8];
            #pragma unroll
            for (int i = 0; i < 4; ++i)
                #pragma unroll
                for (int j = 0; j < 4; ++j)
                    acc[i][j] = __builtin_amdgcn_mfma_f32_16x16x32_bf16(a[i], b[j], acc[i][j], 0, 0, 0);
        }
    }
    #pragma unroll
    for (int i = 0; i < 4; ++i)
        #pragma unroll
        for (int j = 0; j < 4; ++j)
            #pragma unroll
            for (int r = 0; r < 4; ++r) {
                long row = m0 + wr + 16 * i + quad * 4 + r;
                long col = n0 + wc + 16 * j + l15;
                float v = acc[i][j][r];
                if (GEGLU) {
                    float av = bf2f(C[row * ldc + col]);
                    v = 0.5f * av * (1.0f + erff(av * 0.70710678118f)) * v;
                }
                if (ACCUM) v += bf2f(C[row * ldc + col]);
                C[row * ldc + col] = f2bf(v);
            }
}

// ---------------- Flash attention (causal GQA) ----------------
// block = (b, h, 64-row q tile); wave w owns q rows [qs, qs+16).
// qp[T,2048], kp[T,512], vpT[b*512+g*128+d][2048] -> ctx[T,2048]
__global__ __launch_bounds__(256) void attn_kernel(const short* __restrict__ qp, const short* __restrict__ kp,
                                                   const short* __restrict__ vpT, short* __restrict__ ctx) {
    __shared__ short plds[4][16 * 72];       // per-wave private P strip 16x64 (pad 72)
    int bid = blockIdx.x;
    int b = bid >> 9;
    int h = (bid >> 5) & 15;
    int qt = bid & 31;
    int tid = threadIdx.x;
    int w = tid >> 6, lane = tid & 63, quad = lane >> 4, l15 = lane & 15;
    int qs = qt * 64 + w * 16;
    int g = h >> 2;
    const float scale = 0.08838834764831845f;  // 1/sqrt(128)

    bf16x8 qa[4];
    {
        const short* qbase = qp + (long)(b * 2048 + qs + l15) * 2048 + h * 128 + quad * 8;
        #pragma unroll
        for (int c = 0; c < 4; ++c) qa[c] = *(const bf16x8*)(qbase + 32 * c);
    }
    f32x4 o[8] = {};
    float mrow[4], lrow[4], alpha[4];
    #pragma unroll
    for (int r = 0; r < 4; ++r) { mrow[r] = -3e38f; lrow[r] = 0.f; }

    int kend = qs + 16;                       // keys needed: [0, qs+15]
    for (int k0 = 0; k0 < kend; k0 += 64) {
        f32x4 sc[4] = {};
        #pragma unroll
        for (int kt = 0; kt < 4; ++kt) {
            const short* kbase = kp + (long)(b * 2048 + k0 + kt * 16 + l15) * 512 + g * 128 + quad * 8;
            #pragma unroll
            for (int c = 0; c < 4; ++c)
                sc[kt] = __builtin_amdgcn_mfma_f32_16x16x32_bf16(qa[c], *(const bf16x8*)(kbase + 32 * c), sc[kt], 0, 0, 0);
        }
        float mx[4];
        #pragma unroll
        for (int r = 0; r < 4; ++r) mx[r] = -3e38f;
        #pragma unroll
        for (int kt = 0; kt < 4; ++kt)
            #pragma unroll
            for (int r = 0; r < 4; ++r) {
                int key = k0 + kt * 16 + l15;
                int q = qs + quad * 4 + r;
                float sv = sc[kt][r] * scale;
                if (key > q) sv = -1e30f;
                sc[kt][r] = sv;
                mx[r] = fmaxf(mx[r], sv);
            }
        #pragma unroll
        for (int r = 0; r < 4; ++r) {
            #pragma unroll
            for (int off = 8; off; off >>= 1) mx[r] = fmaxf(mx[r], __shfl_xor(mx[r], off, 64));
            float mn = fmaxf(mrow[r], mx[r]);
            alpha[r] = __expf(mrow[r] - mn);
            mrow[r] = mn;
        }
        float ls[4] = {0.f, 0.f, 0.f, 0.f};
        #pragma unroll
        for (int kt = 0; kt < 4; ++kt)
            #pragma unroll
            for (int r = 0; r < 4; ++r) {
                float pv = __expf(sc[kt][r] - mrow[r]);
                ls[r] += pv;
                plds[w][(quad * 4 + r) * 72 + kt * 16 + l15] = f2bf(pv);
            }
        #pragma unroll
        for (int r = 0; r < 4; ++r) {
            #pragma unroll
            for (int off = 8; off; off >>= 1) ls[r] += __shfl_xor(ls[r], off, 64);
            lrow[r] = lrow[r] * alpha[r] + ls[r];
        }
        #pragma unroll
        for (int dt = 0; dt < 8; ++dt)
            #pragma unroll
            for (int r = 0; r < 4; ++r) o[dt][r] *= alpha[r];
        bf16x8 pa0 = *(const bf16x8*)&plds[w][l15 * 72 + quad * 8];
        bf16x8 pa1 = *(const bf16x8*)&plds[w][l15 * 72 + 32 + quad * 8];
        #pragma unroll
        for (int dt = 0; dt < 8; ++dt) {
            const short* vb = vpT + (long)((b * 4 + g) * 128 + dt * 16 + l15) * 2048 + k0 + quad * 8;
            o[dt] = __builtin_amdgcn_mfma_f32_16x16x32_bf16(pa0, *(const bf16x8*)vb,        o[dt], 0, 0, 0);
            o[dt] = __builtin_amdgcn_mfma_f32_16x16x32_bf16(pa1, *(const bf16x8*)(vb + 32), o[dt], 0, 0, 0);
        }
    }
    #pragma unroll
    for (int dt = 0; dt < 8; ++dt)
        #pragma unroll
        for (int r = 0; r < 4; ++r) {
            int q = qs + quad * 4 + r;
            float inv_l = lrow[r] > 0.f ? 1.0f / lrow[r] : 0.f;
            ctx[(long)(b * 2048 + q) * 2048 + h * 128 + dt * 16 + l15] = f2bf(o[dt][r] * inv_l);
        }
}

// ---------------- residual + RMSNorm: out = rms(a+b)*w ----------------
// a,b always internal bf16. w is an external input (fp32 or bf16).
// OUT_ADAPT=1: out follows input dtype; OUT_ADAPT=0: out forced bf16 (internal h).
template<int OUT_ADAPT>
__global__ __launch_bounds__(256) void rmsnorm_res(const short* __restrict__ a, const short* __restrict__ b,
                                                   const void* __restrict__ w, void* __restrict__ out) {
    bool f32 = src_is_f32(w);
    int t = blockIdx.x, tid = threadIdx.x;
    long base = (long)t * 2048 + tid * 8;
    s16x8 av = *(const s16x8*)(a + base);
    s16x8 bv = *(const s16x8*)(b + base);
    float v[8]; float ss = 0.f;
    #pragma unroll
    for (int k = 0; k < 8; ++k) { v[k] = bf2f(av[k]) + bf2f(bv[k]); ss += v[k] * v[k]; }
    #pragma unroll
    for (int off = 32; off; off >>= 1) ss += __shfl_xor(ss, off, 64);
    __shared__ float red[4];
    if ((tid & 63) == 0) red[tid >> 6] = ss;
    __syncthreads();
    float tot = red[0] + red[1] + red[2] + red[3];
    float rs = rsqrtf(tot * (1.0f / 2048.0f) + 1e-6f);
    float wv[8];
    if (f32) {
        #pragma unroll
        for (int k = 0; k < 8; ++k) wv[k] = ((const float*)w)[tid * 8 + k];
    } else {
        s16x8 w8 = *(const s16x8*)((const short*)w + tid * 8);
        #pragma unroll
        for (int k = 0; k < 8; ++k) wv[k] = bf2f(w8[k]);
    }
    if (OUT_ADAPT && f32) {
        float* o = (float*)out;
        #pragma unroll
        for (int k = 0; k < 8; ++k) o[base + k] = v[k] * rs * wv[k];
    } else {
        short* o = (short*)out;
        s16x8 ov;
        #pragma unroll
        for (int k = 0; k < 8; ++k) ov[k] = f2bf(v[k] * rs * wv[k]);
        *(s16x8*)(o + base) = ov;
    }
}

extern "C" void kernel_launch(void* const* d_in, const int* in_sizes, int n_in,
                              void* d_out, int out_size, void* d_ws, size_t ws_size,
                              hipStream_t stream) {
    const void* x     = d_in[0];
    const void* wq    = d_in[1];
    const void* wk    = d_in[2];
    const void* wv    = d_in[3];
    const void* wo    = d_in[4];
    const void* n1w   = d_in[5];
    const void* n2w   = d_in[6];
    const void* w_in  = d_in[7];
    const void* w_out = d_in[8];
    char* ws = (char*)d_ws;
    // ws layout, peak 112MB (all internal buffers bf16):
    //  [0,16)    WT   : transposed weight slice (w_in in quarters, w_out in halves)
    //  [16,80)   act  : gelu(a)*g  [4096,8192]; pre-act tenants (all dead before act):
    //     kp[16,20) vp[20,24) vpT[24,28) ctx[28,44) xbf[44,60) qf[60,76)
    //  [80,96)   qp -> ao -> fc   (serial reuse)
    //  [96,112)  h
    short* WT  = (short*)(ws);
    short* kp  = (short*)(ws + (16ll << 20));
    short* vp  = (short*)(ws + (20ll << 20));
    short* vpT = (short*)(ws + (24ll << 20));
    short* ctx = (short*)(ws + (28ll << 20));
    short* xbf = (short*)(ws + (44ll << 20));
    short* qf  = (short*)(ws + (60ll << 20));
    short* act = (short*)(ws + (16ll << 20));
    short* qp  = (short*)(ws + (80ll << 20));
    short* h   = (short*)(ws + (96ll << 20));
    short* ao = qp; short* fc = qp;

    rope_kernel<<<16384, 256, 0, stream>>>(x, qf, xbf, n1w);

    transpose_any<<<dim3(64, 64), 256, 0, stream>>>(wq, 0, WT, 2048, 2048, 2048, n1w, 0);
    gemm_nt<0, 0><<<dim3(16, 32), 256, 0, stream>>>(qf, 2048, WT, qp, 2048, 4096, 2048, 2048);

    transpose_any<<<dim3(16, 64), 256, 0, stream>>>(wk, 0, WT, 2048, 512, 512, n1w, 0);
    gemm_nt<0, 0><<<dim3(4, 32), 256, 0, stream>>>(qf, 2048, WT, kp, 512, 4096, 512, 2048);

    transpose_any<<<dim3(16, 64), 256, 0, stream>>>(wv, 0, WT, 2048, 512, 512, n1w, 0);
    gemm_nt<0, 0><<<dim3(4, 32), 256, 0, stream>>>(xbf, 2048, WT, vp, 512, 4096, 512, 2048);

    transpose_any<<<dim3(16, 64), 256, 0, stream>>>(vp, 0, vpT, 2048, 512, 512, n1w, 1);
    transpose_any<<<dim3(16, 64), 256, 0, stream>>>(vp + 2048 * 512, 0, vpT + 512 * 2048, 2048, 512, 512, n1w, 1);

    attn_kernel<<<1024, 256, 0, stream>>>(qp, kp, vpT, ctx);

    transpose_any<<<dim3(64, 64), 256, 0, stream>>>(wo, 0, WT, 2048, 2048, 2048, n1w, 0);
    gemm_nt<0, 0><<<dim3(16, 32), 256, 0, stream>>>(ctx, 2048, WT, ao, 2048, 4096, 2048, 2048);

    rmsnorm_res<0><<<4096, 256, 0, stream>>>(xbf, ao, n1w, h);

    // GeGLU MLP: hg = h @ w_in (w_in transposed one quarter at a time); act = gelu(a)*g in-place
    for (int q = 0; q < 4; ++q) {
        transpose_any<<<dim3(128, 64), 256, 0, stream>>>(w_in, (long)q * 4096, WT, 2048, 4096, 16384, n1w, 0);
        if (q < 2)
            gemm_nt<0, 0><<<dim3(32, 32), 256, 0, stream>>>(h, 2048, WT, act + q * 4096, 8192, 4096, 4096, 2048);
        else
            gemm_nt<1, 0><<<dim3(32, 32), 256, 0, stream>>>(h, 2048, WT, act + (q - 2) * 4096, 8192, 4096, 4096, 2048);
    }

    // fc = act @ w_out, K split in halves (w_out transposed one half at a time), bf16 accumulate
    transpose_any<<<dim3(64, 128), 256, 0, stream>>>(w_out, 0, WT, 4096, 2048, 2048, n1w, 0);
    gemm_nt<0, 0><<<dim3(16, 32), 256, 0, stream>>>(act, 8192, WT, fc, 2048, 4096, 2048, 4096);
    transpose_any<<<dim3(64, 128), 256, 0, stream>>>(w_out, (long)4096 * 2048, WT, 4096, 2048, 2048, n1w, 0);
    gemm_nt<0, 1><<<dim3(16, 32), 256, 0, stream>>>(act + 4096, 8192, WT, fc, 2048, 4096, 2048, 4096);

    rmsnorm_res<1><<<4096, 256, 0, stream>>>(h, fc, n2w, d_out);
}

// Round 4
// 1371.830 us; speedup vs baseline: 1.2158x; 1.2158x over previous
//
#include <hip/hip_runtime.h>
#include <hip/hip_bf16.h>

// bf16 carried as short bit-patterns; MFMA frags as __bf16 vectors (gfx950 builtin sig V8y).
typedef __bf16 bf16x8 __attribute__((ext_vector_type(8)));
typedef short  s16x8  __attribute__((ext_vector_type(8)));
typedef float  f32x4  __attribute__((ext_vector_type(4)));

__device__ __forceinline__ float bf2f(short u) {
    unsigned x = ((unsigned)(unsigned short)u) << 16;
    float f; __builtin_memcpy(&f, &x, 4); return f;
}
__device__ __forceinline__ short f2bf(float f) {
    unsigned u; __builtin_memcpy(&u, &f, 4);
    unsigned r = (u + 0x7fff + ((u >> 16) & 1)) >> 16;   // RNE
    return (short)r;
}
// norm1_w/norm2_w == ones(E). fp32 1.0f low short = 0x0000; bf16 1.0 = 0x3F80.
__device__ __forceinline__ bool src_is_f32(const void* ones_w) {
    return ((const unsigned short*)ones_w)[0] == 0;
}
// async global->LDS, 16B per lane; lds base must be wave-uniform (HW: base + lane*16).
__device__ __forceinline__ void gl2lds16(const short* g, short* lds_base) {
    __builtin_amdgcn_global_load_lds((const __attribute__((address_space(1))) void*)g,
                                     (__attribute__((address_space(3))) void*)lds_base, 16, 0, 0);
}

// ---------------- RoPE: qf = rope(x); xbf = bf16 copy of x ----------------
__global__ __launch_bounds__(256) void rope_kernel(const void* __restrict__ xv, short* __restrict__ qf,
                                                   short* __restrict__ xbf, const void* __restrict__ n1w) {
    bool f32 = src_is_f32(n1w);
    int idx = blockIdx.x * 256 + threadIdx.x;      // 4096 tokens * 16 heads * 64 pairs
    int i    = idx & 63;
    int head = (idx >> 6) & 15;
    int t    = idx >> 10;                          // 0..4095
    int pos  = t & 2047;
    float inv = __expf(-9.210340371976184f * (float)i * (1.0f / 64.0f)); // 10000^(-i/64)
    float fr = (float)pos * inv;
    float s, c; sincosf(fr, &s, &c);
    long base = (long)t * 2048 + head * 128 + i;
    float v1, v2;
    if (f32) { v1 = ((const float*)xv)[base]; v2 = ((const float*)xv)[base + 64]; }
    else     { v1 = bf2f(((const short*)xv)[base]); v2 = bf2f(((const short*)xv)[base + 64]); }
    qf[base]      = f2bf(v1 * c - v2 * s);
    qf[base + 64] = f2bf(v2 * c + v1 * s);
    xbf[base]      = f2bf(v1);
    xbf[base + 64] = f2bf(v2);
}

// ---------------- transpose: src[R][C] (elem offset soff, lead dim ld, fp32-or-bf16) -> dst[C][R] bf16 ----------------
__global__ __launch_bounds__(256) void transpose_any(const void* __restrict__ src, long soff, short* __restrict__ dst,
                                                     int R, int C, int ld, const void* __restrict__ n1w, int force_bf16) {
    bool f32 = force_bf16 ? false : src_is_f32(n1w);
    __shared__ short tile[32][33];
    int tx = threadIdx.x & 31, ty = threadIdx.x >> 5;   // 32 x 8
    int c0 = blockIdx.x * 32, r0 = blockIdx.y * 32;
    #pragma unroll
    for (int i = 0; i < 32; i += 8) {
        long p = soff + (long)(r0 + ty + i) * ld + c0 + tx;
        tile[ty + i][tx] = f32 ? f2bf(((const float*)src)[p]) : ((const short*)src)[p];
    }
    __syncthreads();
    #pragma unroll
    for (int i = 0; i < 32; i += 8) dst[(long)(c0 + ty + i) * R + r0 + tx] = tile[tx][ty + i];
}

// ---------------- NT GEMM (m97 structure): C[M,N] = A[M,K] @ Bt[N,K]^T, bf16 in/out, fp32 acc ----------------
// 128x128 tile, BK=64, unpadded LDS, global_load_lds 16B staging.
// GEGLU=1: C already holds 'a'; write gelu_exact(a) * acc. ACCUM=1: C += acc.
template<int GEGLU, int ACCUM>
__global__ __launch_bounds__(256) void gemm_nt(const short* __restrict__ A, int lda, const short* __restrict__ Bt,
                                               short* __restrict__ C, int ldc, int M, int N, int K) {
    __shared__ short As[128 * 64];
    __shared__ short Bs[128 * 64];
    int tid = threadIdx.x;
    int w = tid >> 6, lane = tid & 63, quad = lane >> 4, l15 = lane & 15;
    int m0 = blockIdx.y * 128, n0 = blockIdx.x * 128;
    int wr = (w >> 1) * 64, wc = (w & 1) * 64;
    // staging map: chunk = w*4+c covers 8 rows of 128B; lane -> row chunk*8 + lane/8, col16 = lane%8
    int srow = (lane >> 3), scol = (lane & 7) * 8;
    f32x4 acc[4][4] = {};
    for (int k0 = 0; k0 < K; k0 += 64) {
        __syncthreads();
        #pragma unroll
        for (int c = 0; c < 4; ++c) {
            int chunk = w * 4 + c;
            int row = chunk * 8 + srow;
            gl2lds16(&A [(long)(m0 + row) * lda + k0 + scol], As + chunk * 512);
            gl2lds16(&Bt[(long)(n0 + row) * K   + k0 + scol], Bs + chunk * 512);
        }
        __syncthreads();
        #pragma unroll
        for (int kk = 0; kk < 64; kk += 32) {
            bf16x8 a[4], b[4];
            #pragma unroll
            for (int i = 0; i < 4; ++i) a[i] = *(const bf16x8*)&As[(wr + 16 * i + l15) * 64 + kk + quad * 8];
            #pragma unroll
            for (int j = 0; j < 4; ++j) b[j] = *(const bf16x8*)&Bs[(wc + 16 * j + l15) * 64 + kk + quad * 8];
            #pragma unroll
            for (int i = 0; i < 4; ++i)
                #pragma unroll
                for (int j = 0; j < 4; ++j)
                    acc[i][j] = __builtin_amdgcn_mfma_f32_16x16x32_bf16(a[i], b[j], acc[i][j], 0, 0, 0);
        }
    }
    #pragma unroll
    for (int i = 0; i < 4; ++i)
        #pragma unroll
        for (int j = 0; j < 4; ++j)
            #pragma unroll
            for (int r = 0; r < 4; ++r) {
                long row = m0 + wr + 16 * i + quad * 4 + r;
                long col = n0 + wc + 16 * j + l15;
                float v = acc[i][j][r];
                if (GEGLU) {
                    float av = bf2f(C[row * ldc + col]);
                    v = 0.5f * av * (1.0f + erff(av * 0.70710678118f)) * v;
                }
                if (ACCUM) v += bf2f(C[row * ldc + col]);
                C[row * ldc + col] = f2bf(v);
            }
}

// ---------------- Flash attention (causal GQA), LDS-staged K/V ----------------
// block = (b, h, 64-row q tile), qt reversed for tail balance; wave w owns q rows [qs, qs+16).
// qp[T,2048], kp[T,512], vpT[(b*4+g)*128+d][2048] -> ctx[T,2048]
__global__ __launch_bounds__(256) void attn_kernel(const short* __restrict__ qp, const short* __restrict__ kp,
                                                   const short* __restrict__ vpT, short* __restrict__ ctx) {
    __shared__ short Kt[64 * 128];           // [key][d]  16KB, unpadded
    __shared__ short Vt[128 * 64];           // [d][key]  16KB, unpadded
    __shared__ short plds[4][16 * 72];       // per-wave private P strip 16x64 (pad 72)
    int bid = blockIdx.x;
    int qt = 31 - (bid >> 5);                // heaviest q-tiles first
    int b = (bid >> 4) & 1;
    int h = bid & 15;
    int tid = threadIdx.x;
    int w = tid >> 6, lane = tid & 63, quad = lane >> 4, l15 = lane & 15;
    int qs = qt * 64 + w * 16;
    int g = h >> 2;
    const float scale = 0.08838834764831845f;  // 1/sqrt(128)

    bf16x8 qa[4];
    {
        const short* qbase = qp + (long)(b * 2048 + qs + l15) * 2048 + h * 128 + quad * 8;
        #pragma unroll
        for (int c = 0; c < 4; ++c) qa[c] = *(const bf16x8*)(qbase + 32 * c);
    }
    f32x4 o[8] = {};
    float mrow[4], lrow[4], alpha[4];
    #pragma unroll
    for (int r = 0; r < 4; ++r) { mrow[r] = -3e38f; lrow[r] = 0.f; }

    // staging lane maps
    int krow = lane >> 4, kcol = (lane & 15) * 8;   // K: 1KB chunk = 4 rows of 256B
    int vrow = lane >> 3, vcol = (lane & 7) * 8;    // V: 1KB chunk = 8 rows of 128B

    int kend = qt * 64 + 64;                 // block-uniform; masking handles per-wave causality
    for (int k0 = 0; k0 < kend; k0 += 64) {
        __syncthreads();
        #pragma unroll
        for (int c = 0; c < 4; ++c) {
            int chunk = w * 4 + c;
            gl2lds16(&kp [(long)(b * 2048 + k0 + chunk * 4 + krow) * 512 + g * 128 + kcol], Kt + chunk * 512);
            gl2lds16(&vpT[(long)((b * 4 + g) * 128 + chunk * 8 + vrow) * 2048 + k0 + vcol], Vt + chunk * 512);
        }
        __syncthreads();
        f32x4 sc[4] = {};
        #pragma unroll
        for (int kt = 0; kt < 4; ++kt) {
            const short* kb = &Kt[(kt * 16 + l15) * 128 + quad * 8];
            #pragma unroll
            for (int c = 0; c < 4; ++c)
                sc[kt] = __builtin_amdgcn_mfma_f32_16x16x32_bf16(qa[c], *(const bf16x8*)(kb + 32 * c), sc[kt], 0, 0, 0);
        }
        float mx[4];
        #pragma unroll
        for (int r = 0; r < 4; ++r) mx[r] = -3e38f;
        #pragma unroll
        for (int kt = 0; kt < 4; ++kt)
            #pragma unroll
            for (int r = 0; r < 4; ++r) {
                int key = k0 + kt * 16 + l15;
                int q = qs + quad * 4 + r;
                float sv = sc[kt][r] * scale;
                if (key > q) sv = -1e30f;
                sc[kt][r] = sv;
                mx[r] = fmaxf(mx[r], sv);
            }
        #pragma unroll
        for (int r = 0; r < 4; ++r) {
            #pragma unroll
            for (int off = 8; off; off >>= 1) mx[r] = fmaxf(mx[r], __shfl_xor(mx[r], off, 64));
            float mn = fmaxf(mrow[r], mx[r]);
            alpha[r] = __expf(mrow[r] - mn);
            mrow[r] = mn;
        }
        float ls[4] = {0.f, 0.f, 0.f, 0.f};
        #pragma unroll
        for (int kt = 0; kt < 4; ++kt)
            #pragma unroll
            for (int r = 0; r < 4; ++r) {
                float pv = __expf(sc[kt][r] - mrow[r]);
                ls[r] += pv;
                plds[w][(quad * 4 + r) * 72 + kt * 16 + l15] = f2bf(pv);
            }
        #pragma unroll
        for (int r = 0; r < 4; ++r) {
            #pragma unroll
            for (int off = 8; off; off >>= 1) ls[r] += __shfl_xor(ls[r], off, 64);
            lrow[r] = lrow[r] * alpha[r] + ls[r];
        }
        #pragma unroll
        for (int dt = 0; dt < 8; ++dt)
            #pragma unroll
            for (int r = 0; r < 4; ++r) o[dt][r] *= alpha[r];
        bf16x8 pa0 = *(const bf16x8*)&plds[w][l15 * 72 + quad * 8];
        bf16x8 pa1 = *(const bf16x8*)&plds[w][l15 * 72 + 32 + quad * 8];
        #pragma unroll
        for (int dt = 0; dt < 8; ++dt) {
            const short* vb = &Vt[(dt * 16 + l15) * 64 + quad * 8];
            o[dt] = __builtin_amdgcn_mfma_f32_16x16x32_bf16(pa0, *(const bf16x8*)vb,        o[dt], 0, 0, 0);
            o[dt] = __builtin_amdgcn_mfma_f32_16x16x32_bf16(pa1, *(const bf16x8*)(vb + 32), o[dt], 0, 0, 0);
        }
    }
    #pragma unroll
    for (int dt = 0; dt < 8; ++dt)
        #pragma unroll
        for (int r = 0; r < 4; ++r) {
            int q = qs + quad * 4 + r;
            float inv_l = lrow[r] > 0.f ? 1.0f / lrow[r] : 0.f;
            ctx[(long)(b * 2048 + q) * 2048 + h * 128 + dt * 16 + l15] = f2bf(o[dt][r] * inv_l);
        }
}

// ---------------- residual + RMSNorm: out = rms(a+b)*w ----------------
template<int OUT_ADAPT>
__global__ __launch_bounds__(256) void rmsnorm_res(const short* __restrict__ a, const short* __restrict__ b,
                                                   const void* __restrict__ w, void* __restrict__ out) {
    bool f32 = src_is_f32(w);
    int t = blockIdx.x, tid = threadIdx.x;
    long base = (long)t * 2048 + tid * 8;
    s16x8 av = *(const s16x8*)(a + base);
    s16x8 bv = *(const s16x8*)(b + base);
    float v[8]; float ss = 0.f;
    #pragma unroll
    for (int k = 0; k < 8; ++k) { v[k] = bf2f(av[k]) + bf2f(bv[k]); ss += v[k] * v[k]; }
    #pragma unroll
    for (int off = 32; off; off >>= 1) ss += __shfl_xor(ss, off, 64);
    __shared__ float red[4];
    if ((tid & 63) == 0) red[tid >> 6] = ss;
    __syncthreads();
    float tot = red[0] + red[1] + red[2] + red[3];
    float rs = rsqrtf(tot * (1.0f / 2048.0f) + 1e-6f);
    float wv[8];
    if (f32) {
        #pragma unroll
        for (int k = 0; k < 8; ++k) wv[k] = ((const float*)w)[tid * 8 + k];
    } else {
        s16x8 w8 = *(const s16x8*)((const short*)w + tid * 8);
        #pragma unroll
        for (int k = 0; k < 8; ++k) wv[k] = bf2f(w8[k]);
    }
    if (OUT_ADAPT && f32) {
        float* o = (float*)out;
        #pragma unroll
        for (int k = 0; k < 8; ++k) o[base + k] = v[k] * rs * wv[k];
    } else {
        short* o = (short*)out;
        s16x8 ov;
        #pragma unroll
        for (int k = 0; k < 8; ++k) ov[k] = f2bf(v[k] * rs * wv[k]);
        *(s16x8*)(o + base) = ov;
    }
}

extern "C" void kernel_launch(void* const* d_in, const int* in_sizes, int n_in,
                              void* d_out, int out_size, void* d_ws, size_t ws_size,
                              hipStream_t stream) {
    const void* x     = d_in[0];
    const void* wq    = d_in[1];
    const void* wk    = d_in[2];
    const void* wv    = d_in[3];
    const void* wo    = d_in[4];
    const void* n1w   = d_in[5];
    const void* n2w   = d_in[6];
    const void* w_in  = d_in[7];
    const void* w_out = d_in[8];
    char* ws = (char*)d_ws;
    // ws layout, peak 112MB (all internal buffers bf16):
    //  [0,16)    WT   : transposed weight slice (w_in in quarters, w_out in halves)
    //  [16,80)   act  : gelu(a)*g  [4096,8192]; pre-act tenants (all dead before act):
    //     kp[16,20) vp[20,24) vpT[24,28) ctx[28,44) xbf[44,60) qf[60,76)
    //  [80,96)   qp -> ao -> fc   (serial reuse)
    //  [96,112)  h
    short* WT  = (short*)(ws);
    short* kp  = (short*)(ws + (16ll << 20));
    short* vp  = (short*)(ws + (20ll << 20));
    short* vpT = (short*)(ws + (24ll << 20));
    short* ctx = (short*)(ws + (28ll << 20));
    short* xbf = (short*)(ws + (44ll << 20));
    short* qf  = (short*)(ws + (60ll << 20));
    short* act = (short*)(ws + (16ll << 20));
    short* qp  = (short*)(ws + (80ll << 20));
    short* h   = (short*)(ws + (96ll << 20));
    short* ao = qp; short* fc = qp;

    rope_kernel<<<16384, 256, 0, stream>>>(x, qf, xbf, n1w);

    transpose_any<<<dim3(64, 64), 256, 0, stream>>>(wq, 0, WT, 2048, 2048, 2048, n1w, 0);
    gemm_nt<0, 0><<<dim3(16, 32), 256, 0, stream>>>(qf, 2048, WT, qp, 2048, 4096, 2048, 2048);

    transpose_any<<<dim3(16, 64), 256, 0, stream>>>(wk, 0, WT, 2048, 512, 512, n1w, 0);
    gemm_nt<0, 0><<<dim3(4, 32), 256, 0, stream>>>(qf, 2048, WT, kp, 512, 4096, 512, 2048);

    transpose_any<<<dim3(16, 64), 256, 0, stream>>>(wv, 0, WT, 2048, 512, 512, n1w, 0);
    gemm_nt<0, 0><<<dim3(4, 32), 256, 0, stream>>>(xbf, 2048, WT, vp, 512, 4096, 512, 2048);

    transpose_any<<<dim3(16, 64), 256, 0, stream>>>(vp, 0, vpT, 2048, 512, 512, n1w, 1);
    transpose_any<<<dim3(16, 64), 256, 0, stream>>>(vp + 2048 * 512, 0, vpT + 512 * 2048, 2048, 512, 512, n1w, 1);

    attn_kernel<<<1024, 256, 0, stream>>>(qp, kp, vpT, ctx);

    transpose_any<<<dim3(64, 64), 256, 0, stream>>>(wo, 0, WT, 2048, 2048, 2048, n1w, 0);
    gemm_nt<0, 0><<<dim3(16, 32), 256, 0, stream>>>(ctx, 2048, WT, ao, 2048, 4096, 2048, 2048);

    rmsnorm_res<0><<<4096, 256, 0, stream>>>(xbf, ao, n1w, h);

    // GeGLU MLP: hg = h @ w_in (w_in transposed one quarter at a time); act = gelu(a)*g in-place
    for (int q = 0; q < 4; ++q) {
        transpose_any<<<dim3(128, 64), 256, 0, stream>>>(w_in, (long)q * 4096, WT, 2048, 4096, 16384, n1w, 0);
        if (q < 2)
            gemm_nt<0, 0><<<dim3(32, 32), 256, 0, stream>>>(h, 2048, WT, act + q * 4096, 8192, 4096, 4096, 2048);
        else
            gemm_nt<1, 0><<<dim3(32, 32), 256, 0, stream>>>(h, 2048, WT, act + (q - 2) * 4096, 8192, 4096, 4096, 2048);
    }

    // fc = act @ w_out, K split in halves (w_out transposed one half at a time), bf16 accumulate
    transpose_any<<<dim3(64, 128), 256, 0, stream>>>(w_out, 0, WT, 4096, 2048, 2048, n1w, 0);
    gemm_nt<0, 0><<<dim3(16, 32), 256, 0, stream>>>(act, 8192, WT, fc, 2048, 4096, 2048, 4096);
    transpose_any<<<dim3(64, 128), 256, 0, stream>>>(w_out, (long)4096 * 2048, WT, 4096, 2048, 2048, n1w, 0);
    gemm_nt<0, 1><<<dim3(16, 32), 256, 0, stream>>>(act + 4096, 8192, WT, fc, 2048, 4096, 2048, 4096);

    rmsnorm_res<1><<<4096, 256, 0, stream>>>(h, fc, n2w, d_out);
}